// Round 4
// baseline (81.727 us; speedup 1.0000x reference)
//
#include <hip/hip_runtime.h>

// Y = 2*X elementwise over 8192x8192 fp32, with Y[0][1] = -2*X[0][1].
// Streaming kernel, exact cover: 8192 blocks x 256 threads x 8 float4.
// Loads: cached (want the 256 MiB input resident in Infinity Cache across
// graph replays). Stores: inline-asm global_store_dwordx4 with `sc1 nt`
// (system-scope + non-temporal) so the write-once output stream does not
// allocate in L2 *or* the memory-side Infinity Cache — protecting the
// input's L3 residency (current FETCH shows only 50% of input resident).

typedef float f32x4 __attribute__((ext_vector_type(4)));

#define VPT 8  // float4s per thread

__global__ __launch_bounds__(256) void scale2_kernel(const f32x4* __restrict__ in,
                                                     f32x4* __restrict__ out) {
    // Block covers 256*VPT consecutive float4s; lane i handles base+i, base+i+256, ...
    const int base = blockIdx.x * (256 * VPT) + threadIdx.x;

    f32x4 v[VPT];
#pragma unroll
    for (int k = 0; k < VPT; ++k)
        v[k] = in[base + k * 256];        // 8 independent global_load_dwordx4

#pragma unroll
    for (int k = 0; k < VPT; ++k)
        v[k] *= 2.0f;

    if (base == 0) v[0].y = -v[0].y;      // flat element 1 == .y of vec 0

#pragma unroll
    for (int k = 0; k < VPT; ++k) {
        const f32x4* p = out + base + k * 256;
        // no-allocate at all cache levels: system scope + non-temporal
        asm volatile("global_store_dwordx4 %0, %1, off sc1 nt"
                     :: "v"(p), "v"(v[k]) : "memory");
    }
}

extern "C" void kernel_launch(void* const* d_in, const int* in_sizes, int n_in,
                              void* d_out, int out_size, void* d_ws, size_t ws_size,
                              hipStream_t stream) {
    const f32x4* in = (const f32x4*)d_in[0];
    f32x4* out = (f32x4*)d_out;
    int n = in_sizes[0];            // 8192*8192 = 67,108,864
    int n4 = n / 4;                 // 16,777,216 float4s
    int grid = n4 / (256 * VPT);    // 8192 blocks, exact cover

    scale2_kernel<<<grid, 256, 0, stream>>>(in, out);
}